// Round 9
// baseline (128.998 us; speedup 1.0000x reference)
//
#include <hip/hip_runtime.h>
#include <math.h>

#define NUM_AA   21
#define OUT_DIM  387          // 1 + 21 + 21 + 64 + 42 + 42 + 196
#define SCALE    0.1f
#define EPS_C    1e-8f
#define EPB      32           // edges per block (32*387*4 = 49536 B = 387 cache lines)
#define TPB      1024         // 16 waves; each wave handles 2 edges

typedef float v4f __attribute__((ext_vector_type(4)));

// ---------------- Kernel A: per-node precompute (N=10k, trivial) ------------
// S-struct (64 f, 256 B): [locS 0..41 | rot 42..50 | tS 51..53 | xcaS 54..56 | seqS 57 | pad..63]
// D-struct (48 f, 192 B): [a14d(scaled) 0..41 | xcaD 42..44 | seqD 45 | pad..47]
// ws layout: S structs at WS[0..N*64), D structs at WS[N*64 + n*48)
__global__ __launch_bounds__(256) void node_pre_kernel(
    const float* __restrict__ A, const float* __restrict__ R,
    const float* __restrict__ T, const float* __restrict__ LG,
    float* __restrict__ WS, int N)
{
    const int n = blockIdx.x * 256 + threadIdx.x;
    if (n >= N) return;

    float a14[42];
    #pragma unroll
    for (int k = 0; k < 42; ++k) a14[k] = A[(size_t)n * 42 + k] * SCALE;
    float rot[9];
    #pragma unroll
    for (int k = 0; k < 9; ++k) rot[k] = R[(size_t)n * 9 + k];
    const float t0 = T[(size_t)n * 3 + 0] * SCALE;
    const float t1 = T[(size_t)n * 3 + 1] * SCALE;
    const float t2 = T[(size_t)n * 3 + 2] * SCALE;

    // argmax over 21 logits (first-max wins, matches jnp.argmax)
    const float* lg = LG + (size_t)n * NUM_AA;
    float best = lg[0]; int bi = 0;
    #pragma unroll
    for (int j = 1; j < NUM_AA; ++j) {
        float v = lg[j];
        if (v > best) { best = v; bi = j; }
    }

    float* S = WS + (size_t)n * 64;
    float* D = WS + (size_t)N * 64 + (size_t)n * 48;

    // locS[a,i] = sum_j rot[j*3+i] * (a14[a*3+j] - t[j])
    #pragma unroll
    for (int a = 0; a < 14; ++a) {
        const float x0 = a14[a * 3 + 0] - t0;
        const float x1 = a14[a * 3 + 1] - t1;
        const float x2 = a14[a * 3 + 2] - t2;
        #pragma unroll
        for (int i = 0; i < 3; ++i)
            S[a * 3 + i] = rot[i] * x0 + rot[3 + i] * x1 + rot[6 + i] * x2;
    }
    #pragma unroll
    for (int k = 0; k < 9; ++k) S[42 + k] = rot[k];
    S[51] = t0; S[52] = t1; S[53] = t2;
    S[54] = a14[3]; S[55] = a14[4]; S[56] = a14[5];   // X_ca (scaled)
    S[57] = (float)bi;
    #pragma unroll
    for (int k = 58; k < 64; ++k) S[k] = 0.f;

    #pragma unroll
    for (int k = 0; k < 42; ++k) D[k] = a14[k];
    D[42] = a14[3]; D[43] = a14[4]; D[44] = a14[5];
    D[45] = (float)bi;
    D[46] = 0.f; D[47] = 0.f;
}

// ---------------- per-edge feature computation (gs: S[0..63], D[64..111]) ---
__device__ __forceinline__ void edge_phase1(const float* __restrict__ gs,
                                            float* __restrict__ row, int lane)
{
    {
        const float dx = gs[106] - gs[54];
        const float dy = gs[107] - gs[55];
        const float dz = gs[108] - gs[56];
        const float dca = __builtin_amdgcn_sqrtf(dx * dx + dy * dy + dz * dz);
        const float mu  = (float)lane * (20.0f / 63.0f);
        const float z   = (dca - mu) * 3.2f;   // 1/sigma = 64/20
        row[43 + lane] = __expf(-z * z);
    }
    const int seqS = (int)gs[57];
    const int seqD = (int)gs[109];
    if (lane == 21) row[0] = 1.0f;
    if (lane < 21) {
        row[1  + lane] = (lane == seqS) ? 1.0f : 0.0f;
        row[22 + lane] = (lane == seqD) ? 1.0f : 0.0f;
    }
    if (lane < 42) {
        const int a = lane / 3;
        const int i = lane - a * 3;
        const float r0 = gs[42 + i], r1 = gs[45 + i], r2 = gs[48 + i];
        const float locD = r0 * (gs[64 + a * 3 + 0] - gs[51])
                         + r1 * (gs[64 + a * 3 + 1] - gs[52])
                         + r2 * (gs[64 + a * 3 + 2] - gs[53]);
        row[107 + lane] = gs[lane];    // locS (precomputed)
        row[149 + lane] = locD;
    }
}

__device__ __forceinline__ void edge_phase2(float* __restrict__ row, int lane)
{
    #pragma unroll
    for (int k = 0; k < 4; ++k) {
        const int p = lane + k * 64;
        if (p < 196) {
            const unsigned a = (unsigned)p / 14u;
            const unsigned b = (unsigned)p - a * 14u;
            const float ddx = row[107 + a * 3 + 0] - row[149 + b * 3 + 0] + EPS_C;
            const float ddy = row[107 + a * 3 + 1] - row[149 + b * 3 + 1] + EPS_C;
            const float ddz = row[107 + a * 3 + 2] - row[149 + b * 3 + 2] + EPS_C;
            row[191 + p] = __builtin_amdgcn_sqrtf(ddx * ddx + ddy * ddy + ddz * ddz);
        }
    }
}

// ---------------- Kernel B: per-edge assembly -------------------------------
// 1024 threads = 16 waves; each wave owns 2 edges. Block output region is
// exactly 387 × 128 B (line-aligned) -> cached full-line stores, no RMW,
// no cross-block line sharing.
__global__ __launch_bounds__(1024, 2) void edge_feat_kernel(
    const int*   __restrict__ EI,   // (2,E)  [0]=dst, [1]=src
    const float* __restrict__ WS,   // packed node structs
    float* __restrict__ out,        // (E,387)
    int E, int N)
{
    __shared__ __align__(16) float rowsh[EPB * OUT_DIM];   // 49536 B
    __shared__ __align__(16) float gsh[16][224];           // 14336 B: S0 D0 S1 D1

    const int wv   = threadIdx.x >> 6;
    const int lane = threadIdx.x & 63;
    const int eb   = blockIdx.x * EPB + wv * 2;   // wave's first edge

    int dst0, src0, dst1, src1;
    if (eb + 1 < E) {
        const int2 d = *reinterpret_cast<const int2*>(EI + eb);
        const int2 s = *reinterpret_cast<const int2*>(EI + E + eb);
        dst0 = d.x; dst1 = d.y; src0 = s.x; src1 = s.y;
    } else {
        const int e0c = (eb < E) ? eb : E - 1;
        dst0 = EI[e0c]; src0 = EI[E + e0c];
        dst1 = dst0; src1 = src0;
    }

    float* row0 = rowsh + (size_t)(wv * 2) * OUT_DIM;
    float* row1 = row0 + OUT_DIM;
    float* gs   = gsh[wv];   // S0[0..63] D0[64..111] S1[112..175] D1[176..223]

    // ---- gather: lanes 0-15 S0, 16-27 D0, 28-43 S1, 44-55 D1 (16B each) ----
    {
        const int k   = (lane >= 28) ? 1 : 0;
        const int lr  = lane - k * 28;          // 0..27
        const bool isD = lr >= 16;
        const int sub = isD ? lr - 16 : lr;
        const int node = isD ? (k ? dst1 : dst0) : (k ? src1 : src0);
        const float* p = isD
            ? WS + (size_t)N * 64 + (size_t)node * 48 + sub * 4
            : WS + (size_t)node * 64 + sub * 4;
        if (lane < 56) {
            const v4f v = *reinterpret_cast<const v4f*>(p);
            *reinterpret_cast<v4f*>(&gs[k * 112 + (isD ? 64 : 0) + sub * 4]) = v;
        }
    }
    asm volatile("s_waitcnt lgkmcnt(0)" ::: "memory");
    __builtin_amdgcn_sched_barrier(0);

    // ---- phase 1 for both edges ----
    edge_phase1(gs,       row0, lane);
    edge_phase1(gs + 112, row1, lane);
    asm volatile("s_waitcnt lgkmcnt(0)" ::: "memory");
    __builtin_amdgcn_sched_barrier(0);

    // ---- phase 2 for both edges ----
    edge_phase2(row0, lane);
    edge_phase2(row1, lane);

    // ---- block barrier, then line-aligned cooperative cached flush ----
    asm volatile("s_waitcnt lgkmcnt(0)" ::: "memory");
    __builtin_amdgcn_s_barrier();
    __builtin_amdgcn_sched_barrier(0);

    const long long base = (long long)blockIdx.x * (EPB * OUT_DIM);
    float* ob = out + base;
    const long long remain = (long long)E * OUT_DIM - base;

    if (remain >= (long long)(EPB * OUT_DIM)) {
        const v4f* s4 = reinterpret_cast<const v4f*>(rowsh);
        v4f* o4 = reinterpret_cast<v4f*>(ob);
        #pragma unroll
        for (int r = 0; r < 4; ++r) {
            const int q = threadIdx.x + r * TPB;
            if (q < (EPB * OUT_DIM) / 4)   // 3096 float4s
                o4[q] = s4[q];
        }
    } else if (remain > 0) {
        for (int q = threadIdx.x; q < (int)remain; q += TPB)
            ob[q] = rowsh[q];
    }
}

extern "C" void kernel_launch(void* const* d_in, const int* in_sizes, int n_in,
                              void* d_out, int out_size, void* d_ws, size_t ws_size,
                              hipStream_t stream) {
    const float* A  = (const float*)d_in[0];   // (N,14,3)
    const float* R  = (const float*)d_in[1];   // (N,3,3)
    const float* T  = (const float*)d_in[2];   // (N,3)
    const float* LG = (const float*)d_in[3];   // (N,21)
    const int*   EI = (const int*)d_in[4];     // (2,E)
    float* out = (float*)d_out;
    float* WS  = (float*)d_ws;

    const int N = in_sizes[0] / 42;
    const int E = in_sizes[4] / 2;

    node_pre_kernel<<<(N + 255) / 256, 256, 0, stream>>>(A, R, T, LG, WS, N);

    const int blocks = (E + EPB - 1) / EPB;
    edge_feat_kernel<<<blocks, TPB, 0, stream>>>(EI, WS, out, E, N);
}

// Round 10
// 123.869 us; speedup vs baseline: 1.0414x; 1.0414x over previous
//
#include <hip/hip_runtime.h>
#include <math.h>

#define NUM_AA   21
#define OUT_DIM  387          // 1 + 21 + 21 + 64 + 42 + 42 + 196
#define SCALE    0.1f
#define EPS_C    1e-8f
#define EPB      8            // edges per block (4 waves x 2 edges)
#define TPB      256

typedef float v4f __attribute__((ext_vector_type(4)));
typedef float v2f __attribute__((ext_vector_type(2)));

// ---------------- Kernel A: per-node precompute (N=10k, trivial) ------------
// S-struct (64 f, 256 B): [locS 0..41 | rot 42..50 | tS 51..53 | xcaS 54..56 | seqS 57 | pad..63]
// D-struct (48 f, 192 B): [a14d(scaled) 0..41 | xcaD 42..44 | seqD 45 | pad..47]
// ws layout: S structs at WS[0..N*64), D structs at WS[N*64 + n*48)
__global__ __launch_bounds__(256) void node_pre_kernel(
    const float* __restrict__ A, const float* __restrict__ R,
    const float* __restrict__ T, const float* __restrict__ LG,
    float* __restrict__ WS, int N)
{
    const int n = blockIdx.x * 256 + threadIdx.x;
    if (n >= N) return;

    float a14[42];
    #pragma unroll
    for (int k = 0; k < 42; ++k) a14[k] = A[(size_t)n * 42 + k] * SCALE;
    float rot[9];
    #pragma unroll
    for (int k = 0; k < 9; ++k) rot[k] = R[(size_t)n * 9 + k];
    const float t0 = T[(size_t)n * 3 + 0] * SCALE;
    const float t1 = T[(size_t)n * 3 + 1] * SCALE;
    const float t2 = T[(size_t)n * 3 + 2] * SCALE;

    // argmax over 21 logits (first-max wins, matches jnp.argmax)
    const float* lg = LG + (size_t)n * NUM_AA;
    float best = lg[0]; int bi = 0;
    #pragma unroll
    for (int j = 1; j < NUM_AA; ++j) {
        float v = lg[j];
        if (v > best) { best = v; bi = j; }
    }

    float* S = WS + (size_t)n * 64;
    float* D = WS + (size_t)N * 64 + (size_t)n * 48;

    // locS[a,i] = sum_j rot[j*3+i] * (a14[a*3+j] - t[j])
    #pragma unroll
    for (int a = 0; a < 14; ++a) {
        const float x0 = a14[a * 3 + 0] - t0;
        const float x1 = a14[a * 3 + 1] - t1;
        const float x2 = a14[a * 3 + 2] - t2;
        #pragma unroll
        for (int i = 0; i < 3; ++i)
            S[a * 3 + i] = rot[i] * x0 + rot[3 + i] * x1 + rot[6 + i] * x2;
    }
    #pragma unroll
    for (int k = 0; k < 9; ++k) S[42 + k] = rot[k];
    S[51] = t0; S[52] = t1; S[53] = t2;
    S[54] = a14[3]; S[55] = a14[4]; S[56] = a14[5];   // X_ca (scaled)
    S[57] = (float)bi;
    #pragma unroll
    for (int k = 58; k < 64; ++k) S[k] = 0.f;

    #pragma unroll
    for (int k = 0; k < 42; ++k) D[k] = a14[k];
    D[42] = a14[3]; D[43] = a14[4]; D[44] = a14[5];
    D[45] = (float)bi;
    D[46] = 0.f; D[47] = 0.f;
}

// ---------------- per-edge feature computation (gs: S[0..63], D[64..111]) ---
__device__ __forceinline__ void edge_phase1(const float* __restrict__ gs,
                                            float* __restrict__ row, int lane)
{
    {
        const float dx = gs[106] - gs[54];
        const float dy = gs[107] - gs[55];
        const float dz = gs[108] - gs[56];
        const float dca = __builtin_amdgcn_sqrtf(dx * dx + dy * dy + dz * dz);
        const float mu  = (float)lane * (20.0f / 63.0f);
        const float z   = (dca - mu) * 3.2f;   // 1/sigma = 64/20
        row[43 + lane] = __expf(-z * z);
    }
    const int seqS = (int)gs[57];
    const int seqD = (int)gs[109];
    if (lane == 21) row[0] = 1.0f;
    if (lane < 21) {
        row[1  + lane] = (lane == seqS) ? 1.0f : 0.0f;
        row[22 + lane] = (lane == seqD) ? 1.0f : 0.0f;
    }
    if (lane < 42) {
        const int a = lane / 3;
        const int i = lane - a * 3;
        const float r0 = gs[42 + i], r1 = gs[45 + i], r2 = gs[48 + i];
        const float locD = r0 * (gs[64 + a * 3 + 0] - gs[51])
                         + r1 * (gs[64 + a * 3 + 1] - gs[52])
                         + r2 * (gs[64 + a * 3 + 2] - gs[53]);
        row[107 + lane] = gs[lane];    // locS (precomputed)
        row[149 + lane] = locD;
    }
}

__device__ __forceinline__ void edge_phase2(float* __restrict__ row, int lane)
{
    #pragma unroll
    for (int k = 0; k < 4; ++k) {
        const int p = lane + k * 64;
        if (p < 196) {
            const unsigned a = (unsigned)p / 14u;
            const unsigned b = (unsigned)p - a * 14u;
            const float ddx = row[107 + a * 3 + 0] - row[149 + b * 3 + 0] + EPS_C;
            const float ddy = row[107 + a * 3 + 1] - row[149 + b * 3 + 1] + EPS_C;
            const float ddz = row[107 + a * 3 + 2] - row[149 + b * 3 + 2] + EPS_C;
            row[191 + p] = __builtin_amdgcn_sqrtf(ddx * ddx + ddy * ddy + ddz * ddz);
        }
    }
}

// ---------------- Kernel B: per-edge assembly, NO block barrier -------------
// 256 threads = 4 waves; each wave owns 2 edges and flushes its own 774
// floats with nt dwordx2 stores the moment they're ready. 16 KB LDS ->
// 8 blocks/CU = 32 independent waves/CU at staggered phases -> continuous
// store issue.
__global__ __launch_bounds__(256, 8) void edge_feat_kernel(
    const int*   __restrict__ EI,   // (2,E)  [0]=dst, [1]=src
    const float* __restrict__ WS,   // packed node structs
    float* __restrict__ out,        // (E,387)
    int E, int N)
{
    __shared__ __align__(16) float rowsh[EPB * OUT_DIM];   // 12384 B
    __shared__ __align__(16) float gsh[4][224];            //  3584 B

    const int wv   = threadIdx.x >> 6;
    const int lane = threadIdx.x & 63;
    const int eb   = blockIdx.x * EPB + wv * 2;   // wave's first edge
    if (eb >= E) return;

    int dst0, src0, dst1, src1;
    if (eb + 1 < E) {
        const int2 d = *reinterpret_cast<const int2*>(EI + eb);
        const int2 s = *reinterpret_cast<const int2*>(EI + E + eb);
        dst0 = d.x; dst1 = d.y; src0 = s.x; src1 = s.y;
    } else {
        dst0 = EI[eb]; src0 = EI[E + eb];
        dst1 = dst0; src1 = src0;
    }

    float* row0 = rowsh + (size_t)(wv * 2) * OUT_DIM;
    float* row1 = row0 + OUT_DIM;
    float* gs   = gsh[wv];   // S0[0..63] D0[64..111] S1[112..175] D1[176..223]

    // ---- gather: lanes 0-15 S0, 16-27 D0, 28-43 S1, 44-55 D1 (16B each) ----
    {
        const int k   = (lane >= 28) ? 1 : 0;
        const int lr  = lane - k * 28;          // 0..27
        const bool isD = lr >= 16;
        const int sub = isD ? lr - 16 : lr;
        const int node = isD ? (k ? dst1 : dst0) : (k ? src1 : src0);
        const float* p = isD
            ? WS + (size_t)N * 64 + (size_t)node * 48 + sub * 4
            : WS + (size_t)node * 64 + sub * 4;
        if (lane < 56) {
            const v4f v = *reinterpret_cast<const v4f*>(p);
            *reinterpret_cast<v4f*>(&gs[k * 112 + (isD ? 64 : 0) + sub * 4]) = v;
        }
    }
    asm volatile("s_waitcnt lgkmcnt(0)" ::: "memory");   // intra-wave LDS RAW
    __builtin_amdgcn_sched_barrier(0);

    // ---- phase 1 for both edges ----
    edge_phase1(gs,       row0, lane);
    edge_phase1(gs + 112, row1, lane);
    asm volatile("s_waitcnt lgkmcnt(0)" ::: "memory");
    __builtin_amdgcn_sched_barrier(0);

    // ---- phase 2 for both edges ----
    edge_phase2(row0, lane);
    edge_phase2(row1, lane);
    asm volatile("s_waitcnt lgkmcnt(0)" ::: "memory");   // rows complete
    __builtin_amdgcn_sched_barrier(0);

    // ---- per-wave nt flush: 774 floats = 387 dwordx2 (8B-aligned) ----
    const long long fbase = (long long)eb * OUT_DIM;
    const long long remF  = (long long)E * OUT_DIM - fbase;
    float* ob = out + fbase;

    if (remF >= 2LL * OUT_DIM) {
        const v2f* s2 = reinterpret_cast<const v2f*>(row0);
        v2f* o2 = reinterpret_cast<v2f*>(ob);
        #pragma unroll
        for (int k = 0; k < 7; ++k) {
            const int q = lane + k * 64;
            if (q < OUT_DIM)   // 387 dwordx2 per wave (2 rows)
                __builtin_nontemporal_store(s2[q], o2 + q);
        }
    } else {
        for (int q = lane; q < (int)remF; q += 64)
            __builtin_nontemporal_store(row0[q], ob + q);
    }
}

extern "C" void kernel_launch(void* const* d_in, const int* in_sizes, int n_in,
                              void* d_out, int out_size, void* d_ws, size_t ws_size,
                              hipStream_t stream) {
    const float* A  = (const float*)d_in[0];   // (N,14,3)
    const float* R  = (const float*)d_in[1];   // (N,3,3)
    const float* T  = (const float*)d_in[2];   // (N,3)
    const float* LG = (const float*)d_in[3];   // (N,21)
    const int*   EI = (const int*)d_in[4];     // (2,E)
    float* out = (float*)d_out;
    float* WS  = (float*)d_ws;

    const int N = in_sizes[0] / 42;
    const int E = in_sizes[4] / 2;

    node_pre_kernel<<<(N + 255) / 256, 256, 0, stream>>>(A, R, T, LG, WS, N);

    const int blocks = (E + EPB - 1) / EPB;
    edge_feat_kernel<<<blocks, TPB, 0, stream>>>(EI, WS, out, E, N);
}

// Round 11
// 107.920 us; speedup vs baseline: 1.1953x; 1.1478x over previous
//
#include <hip/hip_runtime.h>
#include <math.h>

#define NUM_AA   21
#define OUT_DIM  387          // 1 + 21 + 21 + 64 + 42 + 42 + 196
#define SCALE    0.1f
#define EPS_C    1e-8f
#define EPB      32           // edges per block (32*387*4 = 49536 B = 387 cache lines)
#define TPB      1024         // 16 waves; each wave handles 2 edges

typedef float v4f __attribute__((ext_vector_type(4)));

// ---------------- Kernel A: per-node precompute (N=10k, trivial) ------------
// S-struct (64 f, 256 B): [locS 0..41 | rot 42..50 | tS 51..53 | xcaS 54..56 | seqS 57 | pad..63]
// D-struct (48 f, 192 B): [a14d(scaled) 0..41 | xcaD 42..44 | seqD 45 | pad..47]
// ws layout: S structs at WS[0..N*64), D structs at WS[N*64 + n*48)
__global__ __launch_bounds__(256) void node_pre_kernel(
    const float* __restrict__ A, const float* __restrict__ R,
    const float* __restrict__ T, const float* __restrict__ LG,
    float* __restrict__ WS, int N)
{
    const int n = blockIdx.x * 256 + threadIdx.x;
    if (n >= N) return;

    float a14[42];
    #pragma unroll
    for (int k = 0; k < 42; ++k) a14[k] = A[(size_t)n * 42 + k] * SCALE;
    float rot[9];
    #pragma unroll
    for (int k = 0; k < 9; ++k) rot[k] = R[(size_t)n * 9 + k];
    const float t0 = T[(size_t)n * 3 + 0] * SCALE;
    const float t1 = T[(size_t)n * 3 + 1] * SCALE;
    const float t2 = T[(size_t)n * 3 + 2] * SCALE;

    // argmax over 21 logits (first-max wins, matches jnp.argmax)
    const float* lg = LG + (size_t)n * NUM_AA;
    float best = lg[0]; int bi = 0;
    #pragma unroll
    for (int j = 1; j < NUM_AA; ++j) {
        float v = lg[j];
        if (v > best) { best = v; bi = j; }
    }

    float* S = WS + (size_t)n * 64;
    float* D = WS + (size_t)N * 64 + (size_t)n * 48;

    // locS[a,i] = sum_j rot[j*3+i] * (a14[a*3+j] - t[j])
    #pragma unroll
    for (int a = 0; a < 14; ++a) {
        const float x0 = a14[a * 3 + 0] - t0;
        const float x1 = a14[a * 3 + 1] - t1;
        const float x2 = a14[a * 3 + 2] - t2;
        #pragma unroll
        for (int i = 0; i < 3; ++i)
            S[a * 3 + i] = rot[i] * x0 + rot[3 + i] * x1 + rot[6 + i] * x2;
    }
    #pragma unroll
    for (int k = 0; k < 9; ++k) S[42 + k] = rot[k];
    S[51] = t0; S[52] = t1; S[53] = t2;
    S[54] = a14[3]; S[55] = a14[4]; S[56] = a14[5];   // X_ca (scaled)
    S[57] = (float)bi;
    #pragma unroll
    for (int k = 58; k < 64; ++k) S[k] = 0.f;

    #pragma unroll
    for (int k = 0; k < 42; ++k) D[k] = a14[k];
    D[42] = a14[3]; D[43] = a14[4]; D[44] = a14[5];
    D[45] = (float)bi;
    D[46] = 0.f; D[47] = 0.f;
}

// ---------------- per-edge feature computation (gs: S[0..63], D[64..111]) ---
__device__ __forceinline__ void edge_phase1(const float* __restrict__ gs,
                                            float* __restrict__ row, int lane)
{
    {
        const float dx = gs[106] - gs[54];
        const float dy = gs[107] - gs[55];
        const float dz = gs[108] - gs[56];
        const float dca = __builtin_amdgcn_sqrtf(dx * dx + dy * dy + dz * dz);
        const float mu  = (float)lane * (20.0f / 63.0f);
        const float z   = (dca - mu) * 3.2f;   // 1/sigma = 64/20
        row[43 + lane] = __expf(-z * z);
    }
    const int seqS = (int)gs[57];
    const int seqD = (int)gs[109];
    if (lane == 21) row[0] = 1.0f;
    if (lane < 21) {
        row[1  + lane] = (lane == seqS) ? 1.0f : 0.0f;
        row[22 + lane] = (lane == seqD) ? 1.0f : 0.0f;
    }
    if (lane < 42) {
        const int a = lane / 3;
        const int i = lane - a * 3;
        const float r0 = gs[42 + i], r1 = gs[45 + i], r2 = gs[48 + i];
        const float locD = r0 * (gs[64 + a * 3 + 0] - gs[51])
                         + r1 * (gs[64 + a * 3 + 1] - gs[52])
                         + r2 * (gs[64 + a * 3 + 2] - gs[53]);
        row[107 + lane] = gs[lane];    // locS (precomputed)
        row[149 + lane] = locD;
    }
}

__device__ __forceinline__ void edge_phase2(float* __restrict__ row, int lane)
{
    #pragma unroll
    for (int k = 0; k < 4; ++k) {
        const int p = lane + k * 64;
        if (p < 196) {
            const unsigned a = (unsigned)p / 14u;
            const unsigned b = (unsigned)p - a * 14u;
            const float ddx = row[107 + a * 3 + 0] - row[149 + b * 3 + 0] + EPS_C;
            const float ddy = row[107 + a * 3 + 1] - row[149 + b * 3 + 1] + EPS_C;
            const float ddz = row[107 + a * 3 + 2] - row[149 + b * 3 + 2] + EPS_C;
            row[191 + p] = __builtin_amdgcn_sqrtf(ddx * ddx + ddy * ddy + ddz * ddz);
        }
    }
}

// ---------------- Kernel B: per-edge assembly -------------------------------
// 1024 threads = 16 waves; each wave owns 2 edges. Block output region is
// exactly 387 × 128 B (line-aligned). Nontemporal dwordx4 cooperative flush.
__global__ __launch_bounds__(1024, 2) void edge_feat_kernel(
    const int*   __restrict__ EI,   // (2,E)  [0]=dst, [1]=src
    const float* __restrict__ WS,   // packed node structs
    float* __restrict__ out,        // (E,387)
    int E, int N)
{
    __shared__ __align__(16) float rowsh[EPB * OUT_DIM];   // 49536 B
    __shared__ __align__(16) float gsh[16][224];           // 14336 B: S0 D0 S1 D1

    const int wv   = threadIdx.x >> 6;
    const int lane = threadIdx.x & 63;
    const int eb   = blockIdx.x * EPB + wv * 2;   // wave's first edge

    int dst0, src0, dst1, src1;
    if (eb + 1 < E) {
        const int2 d = *reinterpret_cast<const int2*>(EI + eb);
        const int2 s = *reinterpret_cast<const int2*>(EI + E + eb);
        dst0 = d.x; dst1 = d.y; src0 = s.x; src1 = s.y;
    } else {
        const int e0c = (eb < E) ? eb : E - 1;
        dst0 = EI[e0c]; src0 = EI[E + e0c];
        dst1 = dst0; src1 = src0;
    }

    float* row0 = rowsh + (size_t)(wv * 2) * OUT_DIM;
    float* row1 = row0 + OUT_DIM;
    float* gs   = gsh[wv];   // S0[0..63] D0[64..111] S1[112..175] D1[176..223]

    // ---- gather: lanes 0-15 S0, 16-27 D0, 28-43 S1, 44-55 D1 (16B each) ----
    {
        const int k   = (lane >= 28) ? 1 : 0;
        const int lr  = lane - k * 28;          // 0..27
        const bool isD = lr >= 16;
        const int sub = isD ? lr - 16 : lr;
        const int node = isD ? (k ? dst1 : dst0) : (k ? src1 : src0);
        const float* p = isD
            ? WS + (size_t)N * 64 + (size_t)node * 48 + sub * 4
            : WS + (size_t)node * 64 + sub * 4;
        if (lane < 56) {
            const v4f v = *reinterpret_cast<const v4f*>(p);
            *reinterpret_cast<v4f*>(&gs[k * 112 + (isD ? 64 : 0) + sub * 4]) = v;
        }
    }
    asm volatile("s_waitcnt lgkmcnt(0)" ::: "memory");
    __builtin_amdgcn_sched_barrier(0);

    // ---- phase 1 for both edges ----
    edge_phase1(gs,       row0, lane);
    edge_phase1(gs + 112, row1, lane);
    asm volatile("s_waitcnt lgkmcnt(0)" ::: "memory");
    __builtin_amdgcn_sched_barrier(0);

    // ---- phase 2 for both edges ----
    edge_phase2(row0, lane);
    edge_phase2(row1, lane);

    // ---- block barrier, then line-aligned cooperative nt flush ----
    asm volatile("s_waitcnt lgkmcnt(0)" ::: "memory");
    __builtin_amdgcn_s_barrier();
    __builtin_amdgcn_sched_barrier(0);

    const long long base = (long long)blockIdx.x * (EPB * OUT_DIM);
    float* ob = out + base;
    const long long remain = (long long)E * OUT_DIM - base;

    if (remain >= (long long)(EPB * OUT_DIM)) {
        const v4f* s4 = reinterpret_cast<const v4f*>(rowsh);
        v4f* o4 = reinterpret_cast<v4f*>(ob);
        #pragma unroll
        for (int r = 0; r < 4; ++r) {
            const int q = threadIdx.x + r * TPB;
            if (q < (EPB * OUT_DIM) / 4)   // 3096 float4s
                __builtin_nontemporal_store(s4[q], o4 + q);
        }
    } else if (remain > 0) {
        for (int q = threadIdx.x; q < (int)remain; q += TPB)
            __builtin_nontemporal_store(rowsh[q], ob + q);
    }
}

extern "C" void kernel_launch(void* const* d_in, const int* in_sizes, int n_in,
                              void* d_out, int out_size, void* d_ws, size_t ws_size,
                              hipStream_t stream) {
    const float* A  = (const float*)d_in[0];   // (N,14,3)
    const float* R  = (const float*)d_in[1];   // (N,3,3)
    const float* T  = (const float*)d_in[2];   // (N,3)
    const float* LG = (const float*)d_in[3];   // (N,21)
    const int*   EI = (const int*)d_in[4];     // (2,E)
    float* out = (float*)d_out;
    float* WS  = (float*)d_ws;

    const int N = in_sizes[0] / 42;
    const int E = in_sizes[4] / 2;

    node_pre_kernel<<<(N + 255) / 256, 256, 0, stream>>>(A, R, T, LG, WS, N);

    const int blocks = (E + EPB - 1) / EPB;
    edge_feat_kernel<<<blocks, TPB, 0, stream>>>(EI, WS, out, E, N);
}